// Round 4
// baseline (431.769 us; speedup 1.0000x reference)
//
#include <hip/hip_runtime.h>
#include <hip/hip_bf16.h>

#define NN 100000
#define DD 128

// Bucketed CSR build: 512 nodes per bucket
#define NPB 512
#define NB 196                     // ceil(100000/512)
#define CAPB 12288                 // pairs/bucket (mean 8192, huge slack)
#define PA_BLOCKS 196              // partA blocks per edge list

typedef unsigned short ushort_t;
typedef unsigned int uint_t;
typedef __attribute__((ext_vector_type(8))) short bf16x8;
typedef __attribute__((ext_vector_type(4))) float f32x4;

__device__ __forceinline__ ushort_t f2bf(float f) {
    uint_t u = __builtin_bit_cast(uint_t, f);
    u += 0x7FFFu + ((u >> 16) & 1u);          // RNE
    return (ushort_t)(u >> 16);
}
__device__ __forceinline__ uint_t pack2bf(float a, float b) {
    return (uint_t)f2bf(a) | ((uint_t)f2bf(b) << 16);
}
__device__ __forceinline__ float bflo(uint_t v) {
    return __builtin_bit_cast(float, v << 16);
}
__device__ __forceinline__ float bfhi(uint_t v) {
    return __builtin_bit_cast(float, v & 0xFFFF0000u);
}

// async global->LDS, 16 B per lane (dest = wave-uniform base + lane*16).
__device__ __forceinline__ void gload16(const ushort_t* g, ushort_t* l) {
    __builtin_amdgcn_global_load_lds(
        (const __attribute__((address_space(1))) void*)g,
        (__attribute__((address_space(3))) void*)l,
        16, 0, 0);
}

// ---------------------------------------------------------------------------
// prep: weight transposes (blocks 0..319) + bcnt zeroing (320..321) +
// zero pad-row NN of h1/h2 (block 322; aggregate redirects out-of-range
// edges there so the accumulate loop needs no per-add guards).
// ---------------------------------------------------------------------------
#define PREP_W_BLOCKS 320
#define PREP_Z_BLOCKS 3
__global__ __launch_bounds__(256) void prep(
    const float* __restrict__ w_proj,
    const float* __restrict__ w_self1, const float* __restrict__ w_neigh1,
    const float* __restrict__ w_self2, const float* __restrict__ w_neigh2,
    ushort_t* __restrict__ wtp, ushort_t* __restrict__ wt1,
    ushort_t* __restrict__ wt2, int* __restrict__ bcnt,
    ushort_t* __restrict__ h1pad, ushort_t* __restrict__ h2pad)
{
    const int bid = blockIdx.x;
    const int tid = threadIdx.x;
    if (bid < PREP_W_BLOCKS) {
        int which = bid >> 6;                 // 0..4
        int t = (bid & 63) * 256 + tid;       // 0..16383
        int n = t >> 7, k = t & 127;
        float v;
        ushort_t* d;
        switch (which) {
            case 0: v = w_proj  [(size_t)k * 128 + n]; d = wtp + (size_t)n * 128 + k;       break;
            case 1: v = w_self1 [(size_t)k * 128 + n]; d = wt1 + (size_t)n * 256 + k;       break;
            case 2: v = w_neigh1[(size_t)k * 128 + n]; d = wt1 + (size_t)n * 256 + 128 + k; break;
            case 3: v = w_self2 [(size_t)k * 128 + n]; d = wt2 + (size_t)n * 256 + k;       break;
            default:v = w_neigh2[(size_t)k * 128 + n]; d = wt2 + (size_t)n * 256 + 128 + k; break;
        }
        *d = f2bf(v);
    } else if (bid < PREP_W_BLOCKS + 2) {
        int i = (bid - PREP_W_BLOCKS) * 256 + tid;
        if (i < 2 * NB) bcnt[i] = 0;
    } else {
        // zero the two pad rows (DD shorts = 64 uints each)
        uint_t* p1 = (uint_t*)h1pad;
        uint_t* p2 = (uint_t*)h2pad;
        if (tid < 64) p1[tid] = 0;
        else if (tid < 128) p2[tid - 64] = 0;
    }
}

// ---------------------------------------------------------------------------
// bf16 MFMA GEMM: out = act( [A | Bm] @ W + bias ), W pre-transposed [n][k].
// 128x128 tile/block, 4 waves x (4x4) 16x16x32 MFMA tiles, BK=32.
// Staging via global_load_lds width=16 (async, no VGPR round-trip):
// A-tile and W-tile are LINEAR [128][32] bf16 (8 KB each) — gload_lds dest
// is wave-uniform base + lane*16, so layout must be linear on both write
// and read sides (rule #21). CVT variant (fp32->bf16, layer 0) keeps
// reg-staging for A only; W always uses gload_lds.
// LDS: At+Wt (16 KB) unioned with epilogue Ot (32 KB) -> 32 KB total.
// ---------------------------------------------------------------------------
template <bool RELU, bool TWO, bool CVT>
__global__ __launch_bounds__(256, 4) void gemm_bf16(
    const void* __restrict__ Av, const ushort_t* __restrict__ Bm,
    const ushort_t* __restrict__ W, const float* __restrict__ bias,
    ushort_t* __restrict__ outp)
{
    __shared__ char smem[32768];
    ushort_t* At = (ushort_t*)smem;             // 128*32*2 = 8192 B
    ushort_t* Wt = (ushort_t*)(smem + 8192);    // 8192 B
    ushort_t* Ot = (ushort_t*)smem;             // epilogue: full 32 KB

    const int tid  = threadIdx.x;
    const int lane = tid & 63;
    const int wav  = tid >> 6;
    const int row0 = blockIdx.x * 128;
    const int m0   = (wav & 1) * 64;
    const int n0   = (wav >> 1) * 64;
    const int KTOT = TWO ? 256 : 128;
    const int NCH  = TWO ? 8 : 4;

    f32x4 acc[4][4];
#pragma unroll
    for (int i = 0; i < 4; ++i)
#pragma unroll
        for (int j = 0; j < 4; ++j) acc[i][j] = (f32x4){0.f, 0.f, 0.f, 0.f};

    const int cl = lane & 15;
    const int q  = lane >> 4;

#pragma unroll 1
    for (int ch = 0; ch < NCH; ++ch) {
        const bool second = TWO && (ch >= 4);
        const int kA = (ch & 3) * 32;
        const int kW = ch * 32;

        if (ch) __syncthreads();   // all ds_reads of prev chunk done

        if constexpr (CVT) {
            // W via async gload_lds; A via reg-stage + convert.
#pragma unroll
            for (int j = 0; j < 2; ++j) {
                int cb = (j * 4 + wav) * 64;
                int c  = cb + lane;
                int r  = c >> 2, k2 = c & 3;
                gload16(W + (size_t)r * KTOT + kW + k2 * 8, Wt + cb * 8);
            }
            uint4 av[2];
            const float* fp = (const float*)Av;
#pragma unroll
            for (int j = 0; j < 2; ++j) {
                int g = tid + 256 * j;
                int r = g >> 2;
                int c = (g & 3) * 8;
                int grow = row0 + r;
                if (grow >= NN) grow = NN - 1;
                float4 f0 = *(const float4*)(fp + (size_t)grow * DD + kA + c);
                float4 f1 = *(const float4*)(fp + (size_t)grow * DD + kA + c + 4);
                av[j].x = pack2bf(f0.x, f0.y);
                av[j].y = pack2bf(f0.z, f0.w);
                av[j].z = pack2bf(f1.x, f1.y);
                av[j].w = pack2bf(f1.z, f1.w);
            }
#pragma unroll
            for (int j = 0; j < 2; ++j) {
                int g = tid + 256 * j;
                int r = g >> 2;
                int c = (g & 3) * 8;
                *(uint4*)(&At[r * 32 + c]) = av[j];
            }
        } else {
            const ushort_t* sp = second ? Bm : (const ushort_t*)Av;
#pragma unroll
            for (int j = 0; j < 2; ++j) {
                int cb = (j * 4 + wav) * 64;
                int c  = cb + lane;
                int r  = c >> 2, k2 = c & 3;
                int grow = row0 + r;
                if (grow >= NN) grow = NN - 1;
                gload16(sp + (size_t)grow * DD + kA + k2 * 8, At + cb * 8);
                gload16(W + (size_t)r * KTOT + kW + k2 * 8, Wt + cb * 8);
            }
        }
        __syncthreads();   // drains vmcnt (gload_lds) + lgkmcnt, then barrier

        bf16x8 af[4], bfr[4];
#pragma unroll
        for (int i = 0; i < 4; ++i)
            af[i] = *(const bf16x8*)(&At[(m0 + i * 16 + cl) * 32 + q * 8]);
#pragma unroll
        for (int j = 0; j < 4; ++j)
            bfr[j] = *(const bf16x8*)(&Wt[(n0 + j * 16 + cl) * 32 + q * 8]);
#pragma unroll
        for (int i = 0; i < 4; ++i)
#pragma unroll
            for (int j = 0; j < 4; ++j)
                acc[i][j] = __builtin_amdgcn_mfma_f32_16x16x32_bf16(
                    af[i], bfr[j], acc[i][j], 0, 0, 0);
    }

    // Epilogue. C/D layout: col=lane&15, row=(lane>>4)*4+reg  [m89/m91]
    __syncthreads();   // all waves done reading At/Wt before Ot overwrites
#pragma unroll
    for (int j = 0; j < 4; ++j) {
        int c = n0 + j * 16 + cl;
        float bv = bias[c];
#pragma unroll
        for (int i = 0; i < 4; ++i) {
#pragma unroll
            for (int reg = 0; reg < 4; ++reg) {
                int r = m0 + i * 16 + 4 * q + reg;
                float v = acc[i][j][reg] + bv;
                if constexpr (RELU) v = fmaxf(v, 0.f);
                Ot[r * 128 + c] = f2bf(v);
            }
        }
    }
    __syncthreads();
    int rows = NN - row0; if (rows > 128) rows = 128;
    for (int t = tid; t < rows * 16; t += 256) {
        int r = t >> 4, c8 = (t & 15) * 8;
        *(uint4*)(outp + (size_t)(row0 + r) * DD + c8) =
            *(const uint4*)(&Ot[r * 128 + c8]);
    }
}

// ---------------------------------------------------------------------------
// partA2: bin BOTH edge lists into 512-node buckets in one launch.
// Pair = (local_dst<<17) | src.  Blocks [0,196)->list 0, [196,392)->list 1.
// ---------------------------------------------------------------------------
__global__ __launch_bounds__(256) void partA2(
    const int* __restrict__ e0s, const int* __restrict__ e0d, int E0,
    const int* __restrict__ e1s, const int* __restrict__ e1d, int E1,
    int* __restrict__ bcnt, uint_t* __restrict__ pairs)
{
    __shared__ int hist[NB];
    __shared__ int base[NB];
    const int tid  = threadIdx.x;
    const int half = blockIdx.x >= PA_BLOCKS;
    const int* __restrict__ src = half ? e1s : e0s;
    const int* __restrict__ dst = half ? e1d : e0d;
    const int E = half ? E1 : E0;
    int* bc = bcnt + half * NB;
    uint_t* pp = pairs + (size_t)half * NB * CAPB;
    const int blk = blockIdx.x - half * PA_BLOCKS;
    const int chunk = (E + PA_BLOCKS - 1) / PA_BLOCKS;
    const int ea = blk * chunk;
    int eb = ea + chunk; if (eb > E) eb = E;

    for (int b = tid; b < NB; b += 256) hist[b] = 0;
    __syncthreads();
    for (int e = ea + tid; e < eb; e += 256)
        atomicAdd(&hist[dst[e] >> 9], 1);
    __syncthreads();
    for (int b = tid; b < NB; b += 256) {
        base[b] = atomicAdd(&bc[b], hist[b]);
        hist[b] = 0;
    }
    __syncthreads();
    for (int e = ea + tid; e < eb; e += 256) {
        int d = dst[e];
        int b = d >> 9;
        int off = atomicAdd(&hist[b], 1);
        int p = base[b] + off;
        if (p < CAPB)
            pp[(size_t)b * CAPB + p] =
                ((uint_t)(d & (NPB - 1)) << 17) | (uint_t)src[e];
    }
}

// ---------------------------------------------------------------------------
// partB: one block per bucket (both lists, 392 blocks). Sort the bucket's
// pairs by local dst in LDS, write the src list back IN PLACE into the
// pairs buffer (coalesced), emit counts[] and offs[].
// ---------------------------------------------------------------------------
__global__ __launch_bounds__(256, 2) void partB(
    uint_t* __restrict__ pairs, const int* __restrict__ bcnt,
    int* __restrict__ counts, int* __restrict__ offs)
{
    __shared__ int cnt[NPB];
    __shared__ int loff[NPB];
    __shared__ int ssc[256];
    __shared__ int image[CAPB];

    const int tid  = threadIdx.x;
    const int half = blockIdx.x >= NB;
    const int b    = blockIdx.x - half * NB;
    const int n0   = b << 9;
    int nb = NN - n0; if (nb > NPB) nb = NPB;
    int tot = bcnt[half * NB + b]; if (tot > CAPB) tot = CAPB;
    uint_t* pb = pairs + (size_t)(half * NB + b) * CAPB;
    const int gbase = (half * NB + b) * CAPB;
    int* cnts  = counts + (size_t)half * NN;
    int* offsl = offs   + (size_t)half * NN;

    for (int n = tid; n < NPB; n += 256) cnt[n] = 0;
    __syncthreads();
    for (int i = tid; i < tot; i += 256)
        atomicAdd(&cnt[pb[i] >> 17], 1);
    __syncthreads();

    // exclusive scan of cnt[0..511] with 256 threads
    int a0 = cnt[2 * tid], a1 = cnt[2 * tid + 1];
    int s = a0 + a1;
    ssc[tid] = s;
    __syncthreads();
    for (int off = 1; off < 256; off <<= 1) {
        int t = 0;
        if (tid >= off) t = ssc[tid - off];
        __syncthreads();
        if (tid >= off) ssc[tid] += t;
        __syncthreads();
    }
    int pre = ssc[tid] - s;
    loff[2 * tid]     = pre;
    loff[2 * tid + 1] = pre + a0;
    __syncthreads();

    for (int n = tid; n < nb; n += 256) {
        cnts[n0 + n]  = cnt[n];
        offsl[n0 + n] = gbase + loff[n];
    }
    for (int n = tid; n < NPB; n += 256) cnt[n] = 0;   // reuse as cursor
    __syncthreads();

    for (int i = tid; i < tot; i += 256) {
        uint_t p = pb[i];
        int ln  = p >> 17;
        int pos = loff[ln] + atomicAdd(&cnt[ln], 1);
        image[pos] = (int)(p & 0x1FFFFu);
    }
    __syncthreads();
    for (int i = tid; i < tot; i += 256) pb[i] = (uint_t)image[i];
}

// ---------------------------------------------------------------------------
// CSR mean-aggregate over bf16 h (register accumulation, no atomics).
// PERSISTENT SLOTS: each 16-lane group handles AGG_NPT=5 nodes (strided by
// nslot), with a rolling 1-deep batch pipeline that crosses node boundaries
// (while batch i is accumulated, batch i+1 — possibly of the NEXT node — is
// in flight). Rationale: mean degree 16 -> only 2 batches/node, so the old
// per-node pipeline drained at every node boundary and every 1.5µs block
// exit (6250 tiny blocks, OccupancyPercent 35%). Out-of-range edges
// redirect to zeroed pad row NN (unguarded adds). Per-node edge order
// unchanged -> bit-exact vs round-3 kernel.
// ---------------------------------------------------------------------------
#define AGG_NPT 5

#define AGG_ISSUE(V)                                                      \
    do {                                                                  \
        int s_[8];                                                        \
        _Pragma("unroll")                                                 \
        for (int u = 0; u < 8; ++u) {                                     \
            int jj = j + u;                                               \
            int jc = jj < cnt ? jj : 0;                                   \
            int sv = (int)csr[start + jc];                                \
            s_[u] = jj < cnt ? sv : NN;                                   \
        }                                                                 \
        _Pragma("unroll")                                                 \
        for (int u = 0; u < 8; ++u)                                       \
            V[u] = *(const uint4*)(hl + (size_t)s_[u] * DD);              \
    } while (0)

#define AGG_ACCUM(V)                                                      \
    do {                                                                  \
        _Pragma("unroll")                                                 \
        for (int u = 0; u < 8; ++u) {                                     \
            a0 += bflo(V[u].x); a1 += bfhi(V[u].x);                       \
            a2 += bflo(V[u].y); a3 += bfhi(V[u].y);                       \
            a4 += bflo(V[u].z); a5 += bfhi(V[u].z);                       \
            a6 += bflo(V[u].w); a7 += bfhi(V[u].w);                       \
        }                                                                 \
    } while (0)

#define AGG_ADV()                                                         \
    do {                                                                  \
        j += 8;                                                           \
        if (j >= cnt) {                                                   \
            ++k; j = 0;                                                   \
            if (k < AGG_NPT) {                                            \
                node  = slot + k * nslot;                                 \
                start = offs[node];                                       \
                cnt   = counts[node];                                     \
            }                                                             \
        }                                                                 \
    } while (0)

#define AGG_FIN(CNT, NODE)                                                \
    do {                                                                  \
        float rinv = 1.0f / (float)((CNT) > 1 ? (CNT) : 1);               \
        uint4 o;                                                          \
        o.x = pack2bf(a0 * rinv, a1 * rinv);                              \
        o.y = pack2bf(a2 * rinv, a3 * rinv);                              \
        o.z = pack2bf(a4 * rinv, a5 * rinv);                              \
        o.w = pack2bf(a6 * rinv, a7 * rinv);                              \
        *(uint4*)(mean + (size_t)(NODE) * DD + lane * 8) = o;             \
        a0 = a1 = a2 = a3 = a4 = a5 = a6 = a7 = 0.f;                      \
    } while (0)

__global__ __launch_bounds__(256) void aggregate_bf16(
    const ushort_t* __restrict__ h, const uint_t* __restrict__ csr,
    const int* __restrict__ offs, const int* __restrict__ counts,
    ushort_t* __restrict__ mean, int nslot)
{
    int gid  = blockIdx.x * 256 + threadIdx.x;
    int slot = gid >> 4;
    if (slot >= nslot) return;
    int lane = gid & 15;
    const ushort_t* __restrict__ hl = h + lane * 8;

    float a0 = 0.f, a1 = 0.f, a2 = 0.f, a3 = 0.f;
    float a4 = 0.f, a5 = 0.f, a6 = 0.f, a7 = 0.f;

    uint4 va[8], vb[8];

    // issue cursor over this slot's node stream (node k = slot + k*nslot;
    // empty nodes contribute one all-pad batch so the stream is uniform)
    int k     = 0;
    int node  = slot;
    int start = offs[node];
    int cnt   = counts[node];
    int j     = 0;

    // prologue: first batch into va
    AGG_ISSUE(va);
    bool lastA = (j + 8 >= cnt); int cntA = cnt; int nodeA = node;
    bool lastB = false;          int cntB = 0;   int nodeB = 0;
    AGG_ADV();

    bool par = false;
    while (true) {
        bool more = (k < AGG_NPT);
        if (!par) {
            if (more) {
                AGG_ISSUE(vb);
                lastB = (j + 8 >= cnt); cntB = cnt; nodeB = node;
                AGG_ADV();
            }
            AGG_ACCUM(va);
            if (lastA) AGG_FIN(cntA, nodeA);
        } else {
            if (more) {
                AGG_ISSUE(va);
                lastA = (j + 8 >= cnt); cntA = cnt; nodeA = node;
                AGG_ADV();
            }
            AGG_ACCUM(vb);
            if (lastB) AGG_FIN(cntB, nodeB);
        }
        if (!more) break;
        par = !par;
    }
}

// ---------------------------------------------------------------------------
// Fused edge scoring on bf16 h3: 16 lanes/edge, uint4 (16 B) loads.
// 2 edges per thread-group -> 4 independent gathers (64 B/lane) in flight.
// ---------------------------------------------------------------------------
__device__ __forceinline__ float dot8(uint4 a, uint4 b) {
    return bflo(a.x) * bflo(b.x) + bfhi(a.x) * bfhi(b.x)
         + bflo(a.y) * bflo(b.y) + bfhi(a.y) * bfhi(b.y)
         + bflo(a.z) * bflo(b.z) + bfhi(a.z) * bfhi(b.z)
         + bflo(a.w) * bflo(b.w) + bfhi(a.w) * bfhi(b.w);
}

__global__ __launch_bounds__(256) void score_both(
    const ushort_t* __restrict__ h,
    const int* __restrict__ ps, const int* __restrict__ pd,
    const int* __restrict__ ns, const int* __restrict__ nd,
    float* __restrict__ out, int EP, int TE)
{
    int gid = blockIdx.x * 256 + threadIdx.x;
    int grp = gid >> 4;
    int e0 = grp * 2;
    if (e0 >= TE) return;
    int lane = gid & 15;
    int e1 = e0 + 1;
    bool has1 = (e1 < TE);
    int ee = has1 ? e1 : e0;

    int s0, d0, s1, d1;
    if (e0 < EP) { s0 = ps[e0]; d0 = pd[e0]; }
    else         { s0 = ns[e0 - EP]; d0 = nd[e0 - EP]; }
    if (ee < EP) { s1 = ps[ee]; d1 = pd[ee]; }
    else         { s1 = ns[ee - EP]; d1 = nd[ee - EP]; }

    const ushort_t* __restrict__ hl = h + lane * 8;
    uint4 va0 = *(const uint4*)(hl + (size_t)s0 * DD);
    uint4 vb0 = *(const uint4*)(hl + (size_t)d0 * DD);
    uint4 va1 = *(const uint4*)(hl + (size_t)s1 * DD);
    uint4 vb1 = *(const uint4*)(hl + (size_t)d1 * DD);

    float r0 = dot8(va0, vb0);
    float r1 = dot8(va1, vb1);
#pragma unroll
    for (int off = 8; off; off >>= 1) {
        r0 += __shfl_down(r0, off, 16);
        r1 += __shfl_down(r1, off, 16);
    }
    if (lane == 0) {
        out[e0] = r0;
        if (has1) out[e1] = r1;
    }
}

// ---------------------------------------------------------------------------

extern "C" void kernel_launch(void* const* d_in, const int* in_sizes, int n_in,
                              void* d_out, int out_size, void* d_ws, size_t ws_size,
                              hipStream_t stream)
{
    const float* feat    = (const float*)d_in[0];
    const int*   e0s     = (const int*)d_in[1];
    const int*   e0d     = (const int*)d_in[2];
    const int*   e1s     = (const int*)d_in[3];
    const int*   e1d     = (const int*)d_in[4];
    const int*   ps      = (const int*)d_in[5];
    const int*   pd      = (const int*)d_in[6];
    const int*   ns      = (const int*)d_in[7];
    const int*   nd      = (const int*)d_in[8];
    const float* w_proj  = (const float*)d_in[9];
    const float* b_proj  = (const float*)d_in[10];
    const float* w_self1 = (const float*)d_in[11];
    const float* w_neigh1= (const float*)d_in[12];
    const float* b1      = (const float*)d_in[13];
    const float* w_self2 = (const float*)d_in[14];
    const float* w_neigh2= (const float*)d_in[15];
    const float* b2      = (const float*)d_in[16];

    float* out = (float*)d_out;

    const size_t NF  = (size_t)NN * DD;
    const size_t NFP = NF + DD;          // +1 pad row (index NN, zeroed)
    char* base = (char*)d_ws;

    // bf16 buffers, NFP*2 bytes each (pad row NN for unguarded aggregate).
    ushort_t* h3   = (ushort_t*)base;
    ushort_t* h1   = h3 + NFP;
    ushort_t* mean = h1 + NFP;
    ushort_t* h2   = mean + NFP;

    uint_t* pairs  = (uint_t*)(h2 + NFP);                // 2*NB*CAPB*4 = 19.3 MB
    int*    bcnt   = (int*)(pairs + (size_t)2 * NB * CAPB);   // [2*NB]
    int*    counts = bcnt + 2 * NB;                      // [2*NN]
    int*    offs   = counts + 2 * NN;                    // [2*NN]
    ushort_t* wts  = (ushort_t*)(offs + 2 * NN);
    ushort_t* wtp = wts;                 // [128][128]
    ushort_t* wt1 = wts + 128 * 128;     // [128][256]
    ushort_t* wt2 = wt1 + 128 * 256;     // [128][256]

    const int E0 = in_sizes[1];
    const int E1 = in_sizes[3];
    const int EP = in_sizes[5];
    const int EN = in_sizes[7];

    const int GB    = (NN + 127) / 128;       // 782
    const int NSLOT = NN / AGG_NPT;           // 20000 (exact: 100000/5)
    const int AGB   = (NSLOT * 16 + 255) / 256;   // 1250

    // ---- Prep: weight transposes + bcnt zero + pad-row zero
    prep<<<PREP_W_BLOCKS + PREP_Z_BLOCKS, 256, 0, stream>>>(
        w_proj, w_self1, w_neigh1, w_self2, w_neigh2, wtp, wt1, wt2, bcnt,
        h1 + NF, h2 + NF);

    // ---- Build both CSRs up front
    partA2<<<2 * PA_BLOCKS, 256, 0, stream>>>(
        e0s, e0d, E0, e1s, e1d, E1, bcnt, pairs);
    partB<<<2 * NB, 256, 0, stream>>>(pairs, bcnt, counts, offs);

    // ---- Layer 0: h1 = relu(feat @ w_proj + b_proj), fp32->bf16 fused
    gemm_bf16<true, false, true><<<GB, 256, 0, stream>>>(
        feat, nullptr, wtp, b_proj, h1);

    // ---- Layer 1: mean over edge0, then dual GEMM
    aggregate_bf16<<<AGB, 256, 0, stream>>>(h1, pairs, offs, counts, mean, NSLOT);
    gemm_bf16<true, true, false><<<GB, 256, 0, stream>>>(
        h1, mean, wt1, b1, h2);

    // ---- Layer 2: mean over edge1, then dual GEMM
    aggregate_bf16<<<AGB, 256, 0, stream>>>(
        h2, pairs, offs + NN, counts + NN, mean, NSLOT);
    gemm_bf16<false, true, false><<<GB, 256, 0, stream>>>(
        h2, mean, wt2, b2, h3);

    // ---- Fused scoring on bf16 h3
    const int TE = EP + EN;
    const int NG = (TE + 1) / 2;
    score_both<<<(NG * 16 + 255) / 256, 256, 0, stream>>>(
        h3, ps, pd, ns, nd, out, EP, TE);
}

// Round 6
// 398.836 us; speedup vs baseline: 1.0826x; 1.0826x over previous
//
#include <hip/hip_runtime.h>
#include <hip/hip_bf16.h>

#define NN 100000
#define DD 128

// Bucketed CSR build: 512 nodes per bucket
#define NPB 512
#define NB 196                     // ceil(100000/512)
#define CAPB 12288                 // pairs/bucket (mean 8192, huge slack)
#define PA_BLOCKS 196              // partA blocks per edge list

typedef unsigned short ushort_t;
typedef unsigned int uint_t;
typedef __attribute__((ext_vector_type(8))) short bf16x8;
typedef __attribute__((ext_vector_type(4))) float f32x4;

__device__ __forceinline__ ushort_t f2bf(float f) {
    uint_t u = __builtin_bit_cast(uint_t, f);
    u += 0x7FFFu + ((u >> 16) & 1u);          // RNE
    return (ushort_t)(u >> 16);
}
__device__ __forceinline__ uint_t pack2bf(float a, float b) {
    return (uint_t)f2bf(a) | ((uint_t)f2bf(b) << 16);
}
__device__ __forceinline__ float bflo(uint_t v) {
    return __builtin_bit_cast(float, v << 16);
}
__device__ __forceinline__ float bfhi(uint_t v) {
    return __builtin_bit_cast(float, v & 0xFFFF0000u);
}

// async global->LDS, 16 B per lane (dest = wave-uniform base + lane*16).
__device__ __forceinline__ void gload16(const ushort_t* g, ushort_t* l) {
    __builtin_amdgcn_global_load_lds(
        (const __attribute__((address_space(1))) void*)g,
        (__attribute__((address_space(3))) void*)l,
        16, 0, 0);
}

// ---------------------------------------------------------------------------
// prep: weight transposes (blocks 0..319) + bcnt zeroing (320..321) +
// zero pad-row NN of h1/h2 (block 322; aggregate redirects out-of-range
// edges there so the accumulate loop needs no per-add guards).
// ---------------------------------------------------------------------------
#define PREP_W_BLOCKS 320
#define PREP_Z_BLOCKS 3
__global__ __launch_bounds__(256) void prep(
    const float* __restrict__ w_proj,
    const float* __restrict__ w_self1, const float* __restrict__ w_neigh1,
    const float* __restrict__ w_self2, const float* __restrict__ w_neigh2,
    ushort_t* __restrict__ wtp, ushort_t* __restrict__ wt1,
    ushort_t* __restrict__ wt2, int* __restrict__ bcnt,
    ushort_t* __restrict__ h1pad, ushort_t* __restrict__ h2pad)
{
    const int bid = blockIdx.x;
    const int tid = threadIdx.x;
    if (bid < PREP_W_BLOCKS) {
        int which = bid >> 6;                 // 0..4
        int t = (bid & 63) * 256 + tid;       // 0..16383
        int n = t >> 7, k = t & 127;
        float v;
        ushort_t* d;
        switch (which) {
            case 0: v = w_proj  [(size_t)k * 128 + n]; d = wtp + (size_t)n * 128 + k;       break;
            case 1: v = w_self1 [(size_t)k * 128 + n]; d = wt1 + (size_t)n * 256 + k;       break;
            case 2: v = w_neigh1[(size_t)k * 128 + n]; d = wt1 + (size_t)n * 256 + 128 + k; break;
            case 3: v = w_self2 [(size_t)k * 128 + n]; d = wt2 + (size_t)n * 256 + k;       break;
            default:v = w_neigh2[(size_t)k * 128 + n]; d = wt2 + (size_t)n * 256 + 128 + k; break;
        }
        *d = f2bf(v);
    } else if (bid < PREP_W_BLOCKS + 2) {
        int i = (bid - PREP_W_BLOCKS) * 256 + tid;
        if (i < 2 * NB) bcnt[i] = 0;
    } else {
        // zero the two pad rows (DD shorts = 64 uints each)
        uint_t* p1 = (uint_t*)h1pad;
        uint_t* p2 = (uint_t*)h2pad;
        if (tid < 64) p1[tid] = 0;
        else if (tid < 128) p2[tid - 64] = 0;
    }
}

// ---------------------------------------------------------------------------
// bf16 MFMA GEMM: out = act( [A | Bm] @ W + bias ), W pre-transposed [n][k].
// 128x128 tile/block, 4 waves x (4x4) 16x16x32 MFMA tiles, BK=32.
// Non-CVT path: 2-PHASE double-buffered staging (T3-minimum recipe):
//   prologue STAGE(buf0); vmcnt(0); barrier;
//   loop { STAGE(buf^1, ch+1); COMPUTE(buf); vmcnt(0); barrier; }
//   final COMPUTE — prefetch latency hides under the 16 MFMAs instead of
//   the old stage -> syncthreads(vmcnt-drain) -> compute serialization.
// LDS: 2 x (At 8KB + Wt 8KB) = 32 KB, unioned with epilogue Ot (32 KB).
// CVT variant (fp32->bf16, layer 0) keeps the proven single-buffer path.
// ---------------------------------------------------------------------------
template <bool RELU, bool TWO, bool CVT>
__global__ __launch_bounds__(256, 4) void gemm_bf16(
    const void* __restrict__ Av, const ushort_t* __restrict__ Bm,
    const ushort_t* __restrict__ W, const float* __restrict__ bias,
    ushort_t* __restrict__ outp)
{
    __shared__ char smem[32768];
    ushort_t* Ot = (ushort_t*)smem;             // epilogue: full 32 KB

    const int tid  = threadIdx.x;
    const int lane = tid & 63;
    const int wav  = tid >> 6;
    const int row0 = blockIdx.x * 128;
    const int m0   = (wav & 1) * 64;
    const int n0   = (wav >> 1) * 64;
    const int KTOT = TWO ? 256 : 128;
    const int NCH  = TWO ? 8 : 4;

    f32x4 acc[4][4];
#pragma unroll
    for (int i = 0; i < 4; ++i)
#pragma unroll
        for (int j = 0; j < 4; ++j) acc[i][j] = (f32x4){0.f, 0.f, 0.f, 0.f};

    const int cl = lane & 15;
    const int q  = lane >> 4;

    if constexpr (CVT) {
        // ---- single-buffer path (layer 0): W via gload_lds, A reg-converted
        ushort_t* At = (ushort_t*)smem;             // 128*32*2 = 8192 B
        ushort_t* Wt = (ushort_t*)(smem + 8192);    // 8192 B
#pragma unroll 1
        for (int ch = 0; ch < NCH; ++ch) {
            const int kA = (ch & 3) * 32;
            const int kW = ch * 32;

            if (ch) __syncthreads();
#pragma unroll
            for (int j = 0; j < 2; ++j) {
                int cb = (j * 4 + wav) * 64;
                int c  = cb + lane;
                int r  = c >> 2, k2 = c & 3;
                gload16(W + (size_t)r * KTOT + kW + k2 * 8, Wt + cb * 8);
            }
            uint4 av[2];
            const float* fp = (const float*)Av;
#pragma unroll
            for (int j = 0; j < 2; ++j) {
                int g = tid + 256 * j;
                int r = g >> 2;
                int c = (g & 3) * 8;
                int grow = row0 + r;
                if (grow >= NN) grow = NN - 1;
                float4 f0 = *(const float4*)(fp + (size_t)grow * DD + kA + c);
                float4 f1 = *(const float4*)(fp + (size_t)grow * DD + kA + c + 4);
                av[j].x = pack2bf(f0.x, f0.y);
                av[j].y = pack2bf(f0.z, f0.w);
                av[j].z = pack2bf(f1.x, f1.y);
                av[j].w = pack2bf(f1.z, f1.w);
            }
#pragma unroll
            for (int j = 0; j < 2; ++j) {
                int g = tid + 256 * j;
                int r = g >> 2;
                int c = (g & 3) * 8;
                *(uint4*)(&At[r * 32 + c]) = av[j];
            }
            __syncthreads();

            bf16x8 af[4], bfr[4];
#pragma unroll
            for (int i = 0; i < 4; ++i)
                af[i] = *(const bf16x8*)(&At[(m0 + i * 16 + cl) * 32 + q * 8]);
#pragma unroll
            for (int j = 0; j < 4; ++j)
                bfr[j] = *(const bf16x8*)(&Wt[(n0 + j * 16 + cl) * 32 + q * 8]);
#pragma unroll
            for (int i = 0; i < 4; ++i)
#pragma unroll
                for (int j = 0; j < 4; ++j)
                    acc[i][j] = __builtin_amdgcn_mfma_f32_16x16x32_bf16(
                        af[i], bfr[j], acc[i][j], 0, 0, 0);
        }
    } else {
        // ---- 2-phase double-buffered path (layers 1/2)
        auto STAGE = [&](int ch, int buf) {
            const bool second = TWO && (ch >= 4);
            const int kA = (ch & 3) * 32;
            const int kW = ch * 32;
            ushort_t* At = (ushort_t*)(smem + buf * 16384);
            ushort_t* Wt = At + 4096;            // +8192 bytes
            const ushort_t* sp = second ? Bm : (const ushort_t*)Av;
#pragma unroll
            for (int j = 0; j < 2; ++j) {
                int cb = (j * 4 + wav) * 64;
                int c  = cb + lane;
                int r  = c >> 2, k2 = c & 3;
                int grow = row0 + r;
                if (grow >= NN) grow = NN - 1;
                gload16(sp + (size_t)grow * DD + kA + k2 * 8, At + cb * 8);
                gload16(W + (size_t)r * KTOT + kW + k2 * 8, Wt + cb * 8);
            }
        };
        auto COMPUTE = [&](int buf) {
            ushort_t* At = (ushort_t*)(smem + buf * 16384);
            ushort_t* Wt = At + 4096;
            bf16x8 af[4], bfr[4];
#pragma unroll
            for (int i = 0; i < 4; ++i)
                af[i] = *(const bf16x8*)(&At[(m0 + i * 16 + cl) * 32 + q * 8]);
#pragma unroll
            for (int j = 0; j < 4; ++j)
                bfr[j] = *(const bf16x8*)(&Wt[(n0 + j * 16 + cl) * 32 + q * 8]);
#pragma unroll
            for (int i = 0; i < 4; ++i)
#pragma unroll
                for (int j = 0; j < 4; ++j)
                    acc[i][j] = __builtin_amdgcn_mfma_f32_16x16x32_bf16(
                        af[i], bfr[j], acc[i][j], 0, 0, 0);
        };

        STAGE(0, 0);
        asm volatile("s_waitcnt vmcnt(0)" ::: "memory");
        __builtin_amdgcn_s_barrier();
        int cur = 0;
#pragma unroll 1
        for (int ch = 0; ch < NCH - 1; ++ch) {
            STAGE(ch + 1, cur ^ 1);   // issue next-chunk loads (other buffer)
            COMPUTE(cur);             // ds_read+MFMA current (lgkm waits via deps)
            asm volatile("s_waitcnt vmcnt(0)" ::: "memory");
            __builtin_amdgcn_s_barrier();
            cur ^= 1;
        }
        COMPUTE(cur);                 // last chunk, no prefetch
    }

    // Epilogue. C/D layout: col=lane&15, row=(lane>>4)*4+reg  [m89/m91]
    __syncthreads();   // all waves done reading staging LDS before Ot overwrites
#pragma unroll
    for (int j = 0; j < 4; ++j) {
        int c = n0 + j * 16 + cl;
        float bv = bias[c];
#pragma unroll
        for (int i = 0; i < 4; ++i) {
#pragma unroll
            for (int reg = 0; reg < 4; ++reg) {
                int r = m0 + i * 16 + 4 * q + reg;
                float v = acc[i][j][reg] + bv;
                if constexpr (RELU) v = fmaxf(v, 0.f);
                Ot[r * 128 + c] = f2bf(v);
            }
        }
    }
    __syncthreads();
    int rows = NN - row0; if (rows > 128) rows = 128;
    for (int t = tid; t < rows * 16; t += 256) {
        int r = t >> 4, c8 = (t & 15) * 8;
        *(uint4*)(outp + (size_t)(row0 + r) * DD + c8) =
            *(const uint4*)(&Ot[r * 128 + c8]);
    }
}

// ---------------------------------------------------------------------------
// partA2: bin BOTH edge lists into 512-node buckets in one launch.
// Pair = (local_dst<<17) | src.  Blocks [0,196)->list 0, [196,392)->list 1.
// ---------------------------------------------------------------------------
__global__ __launch_bounds__(256) void partA2(
    const int* __restrict__ e0s, const int* __restrict__ e0d, int E0,
    const int* __restrict__ e1s, const int* __restrict__ e1d, int E1,
    int* __restrict__ bcnt, uint_t* __restrict__ pairs)
{
    __shared__ int hist[NB];
    __shared__ int base[NB];
    const int tid  = threadIdx.x;
    const int half = blockIdx.x >= PA_BLOCKS;
    const int* __restrict__ src = half ? e1s : e0s;
    const int* __restrict__ dst = half ? e1d : e0d;
    const int E = half ? E1 : E0;
    int* bc = bcnt + half * NB;
    uint_t* pp = pairs + (size_t)half * NB * CAPB;
    const int blk = blockIdx.x - half * PA_BLOCKS;
    const int chunk = (E + PA_BLOCKS - 1) / PA_BLOCKS;
    const int ea = blk * chunk;
    int eb = ea + chunk; if (eb > E) eb = E;

    for (int b = tid; b < NB; b += 256) hist[b] = 0;
    __syncthreads();
    for (int e = ea + tid; e < eb; e += 256)
        atomicAdd(&hist[dst[e] >> 9], 1);
    __syncthreads();
    for (int b = tid; b < NB; b += 256) {
        base[b] = atomicAdd(&bc[b], hist[b]);
        hist[b] = 0;
    }
    __syncthreads();
    for (int e = ea + tid; e < eb; e += 256) {
        int d = dst[e];
        int b = d >> 9;
        int off = atomicAdd(&hist[b], 1);
        int p = base[b] + off;
        if (p < CAPB)
            pp[(size_t)b * CAPB + p] =
                ((uint_t)(d & (NPB - 1)) << 17) | (uint_t)src[e];
    }
}

// ---------------------------------------------------------------------------
// partB: one block per bucket (both lists, 392 blocks). Sort the bucket's
// pairs by local dst in LDS, write the src list back IN PLACE into the
// pairs buffer (coalesced), emit counts[] and offs[].
// ---------------------------------------------------------------------------
__global__ __launch_bounds__(256, 2) void partB(
    uint_t* __restrict__ pairs, const int* __restrict__ bcnt,
    int* __restrict__ counts, int* __restrict__ offs)
{
    __shared__ int cnt[NPB];
    __shared__ int loff[NPB];
    __shared__ int ssc[256];
    __shared__ int image[CAPB];

    const int tid  = threadIdx.x;
    const int half = blockIdx.x >= NB;
    const int b    = blockIdx.x - half * NB;
    const int n0   = b << 9;
    int nb = NN - n0; if (nb > NPB) nb = NPB;
    int tot = bcnt[half * NB + b]; if (tot > CAPB) tot = CAPB;
    uint_t* pb = pairs + (size_t)(half * NB + b) * CAPB;
    const int gbase = (half * NB + b) * CAPB;
    int* cnts  = counts + (size_t)half * NN;
    int* offsl = offs   + (size_t)half * NN;

    for (int n = tid; n < NPB; n += 256) cnt[n] = 0;
    __syncthreads();
    for (int i = tid; i < tot; i += 256)
        atomicAdd(&cnt[pb[i] >> 17], 1);
    __syncthreads();

    // exclusive scan of cnt[0..511] with 256 threads
    int a0 = cnt[2 * tid], a1 = cnt[2 * tid + 1];
    int s = a0 + a1;
    ssc[tid] = s;
    __syncthreads();
    for (int off = 1; off < 256; off <<= 1) {
        int t = 0;
        if (tid >= off) t = ssc[tid - off];
        __syncthreads();
        if (tid >= off) ssc[tid] += t;
        __syncthreads();
    }
    int pre = ssc[tid] - s;
    loff[2 * tid]     = pre;
    loff[2 * tid + 1] = pre + a0;
    __syncthreads();

    for (int n = tid; n < nb; n += 256) {
        cnts[n0 + n]  = cnt[n];
        offsl[n0 + n] = gbase + loff[n];
    }
    for (int n = tid; n < NPB; n += 256) cnt[n] = 0;   // reuse as cursor
    __syncthreads();

    for (int i = tid; i < tot; i += 256) {
        uint_t p = pb[i];
        int ln  = p >> 17;
        int pos = loff[ln] + atomicAdd(&cnt[ln], 1);
        image[pos] = (int)(p & 0x1FFFFu);
    }
    __syncthreads();
    for (int i = tid; i < tot; i += 256) pb[i] = (uint_t)image[i];
}

// ---------------------------------------------------------------------------
// CSR mean-aggregate over bf16 h (round-3 version — best measured, 61 µs).
// 16 lanes/node, uint4 (16 B)/lane. Software-pipelined two 8-deep batches.
// Out-of-range edges redirect to zeroed pad row NN (unguarded adds).
// Rounds 2-4 established: more MLP = null, fewer guards = null, less TLP =
// regression -> this shape is at the random-gather service-rate ceiling
// (~6.7 TB/s delivered, ~2.9 TB/s L2-fill).
// ---------------------------------------------------------------------------
#define AGG_ISSUE(V, J)                                                   \
    do {                                                                  \
        int s_[8];                                                        \
        _Pragma("unroll")                                                 \
        for (int u = 0; u < 8; ++u) {                                     \
            int jj = (J) + u;                                             \
            int jc = jj < cnt ? jj : cnt - 1;                             \
            int sv = (int)csr[start + jc];                                \
            s_[u] = jj < cnt ? sv : NN;                                   \
        }                                                                 \
        _Pragma("unroll")                                                 \
        for (int u = 0; u < 8; ++u)                                       \
            V[u] = *(const uint4*)(hl + (size_t)s_[u] * DD);              \
    } while (0)

#define AGG_ACCUM(V)                                                      \
    do {                                                                  \
        _Pragma("unroll")                                                 \
        for (int u = 0; u < 8; ++u) {                                     \
            a0 += bflo(V[u].x); a1 += bfhi(V[u].x);                       \
            a2 += bflo(V[u].y); a3 += bfhi(V[u].y);                       \
            a4 += bflo(V[u].z); a5 += bfhi(V[u].z);                       \
            a6 += bflo(V[u].w); a7 += bfhi(V[u].w);                       \
        }                                                                 \
    } while (0)

__global__ __launch_bounds__(256) void aggregate_bf16(
    const ushort_t* __restrict__ h, const uint_t* __restrict__ csr,
    const int* __restrict__ offs, const int* __restrict__ counts,
    ushort_t* __restrict__ mean, int nn)
{
    int gid  = blockIdx.x * 256 + threadIdx.x;
    int node = gid >> 4;
    if (node >= nn) return;
    int lane  = gid & 15;
    int start = offs[node];
    int cnt   = counts[node];
    const ushort_t* __restrict__ hl = h + lane * 8;

    float a0 = 0.f, a1 = 0.f, a2 = 0.f, a3 = 0.f;
    float a4 = 0.f, a5 = 0.f, a6 = 0.f, a7 = 0.f;

    int nbt = (cnt + 7) >> 3;        // number of (padded) 8-batches
    if (nbt > 0) {
        uint4 va[8], vb[8];
        AGG_ISSUE(va, 0);
        int j = 8, b = 1;
        for (; b + 1 < nbt; b += 2) {
            AGG_ISSUE(vb, j); j += 8;      // batch B in flight...
            AGG_ACCUM(va);                 // ...while A is consumed
            AGG_ISSUE(va, j); j += 8;
            AGG_ACCUM(vb);
        }
        if (b < nbt) {                     // one trailing issued batch
            AGG_ISSUE(vb, j);
            AGG_ACCUM(va);
            AGG_ACCUM(vb);
        } else {
            AGG_ACCUM(va);
        }
    }

    float rinv = 1.0f / (float)(cnt > 1 ? cnt : 1);
    uint4 o;
    o.x = pack2bf(a0 * rinv, a1 * rinv);
    o.y = pack2bf(a2 * rinv, a3 * rinv);
    o.z = pack2bf(a4 * rinv, a5 * rinv);
    o.w = pack2bf(a6 * rinv, a7 * rinv);
    *(uint4*)(mean + (size_t)node * DD + lane * 8) = o;
}

// ---------------------------------------------------------------------------
// Fused edge scoring on bf16 h3: 16 lanes/edge, uint4 (16 B) loads.
// 2 edges per thread-group -> 4 independent gathers (64 B/lane) in flight.
// ---------------------------------------------------------------------------
__device__ __forceinline__ float dot8(uint4 a, uint4 b) {
    return bflo(a.x) * bflo(b.x) + bfhi(a.x) * bfhi(b.x)
         + bflo(a.y) * bflo(b.y) + bfhi(a.y) * bfhi(b.y)
         + bflo(a.z) * bflo(b.z) + bfhi(a.z) * bfhi(b.z)
         + bflo(a.w) * bflo(b.w) + bfhi(a.w) * bfhi(b.w);
}

__global__ __launch_bounds__(256) void score_both(
    const ushort_t* __restrict__ h,
    const int* __restrict__ ps, const int* __restrict__ pd,
    const int* __restrict__ ns, const int* __restrict__ nd,
    float* __restrict__ out, int EP, int TE)
{
    int gid = blockIdx.x * 256 + threadIdx.x;
    int grp = gid >> 4;
    int e0 = grp * 2;
    if (e0 >= TE) return;
    int lane = gid & 15;
    int e1 = e0 + 1;
    bool has1 = (e1 < TE);
    int ee = has1 ? e1 : e0;

    int s0, d0, s1, d1;
    if (e0 < EP) { s0 = ps[e0]; d0 = pd[e0]; }
    else         { s0 = ns[e0 - EP]; d0 = nd[e0 - EP]; }
    if (ee < EP) { s1 = ps[ee]; d1 = pd[ee]; }
    else         { s1 = ns[ee - EP]; d1 = nd[ee - EP]; }

    const ushort_t* __restrict__ hl = h + lane * 8;
    uint4 va0 = *(const uint4*)(hl + (size_t)s0 * DD);
    uint4 vb0 = *(const uint4*)(hl + (size_t)d0 * DD);
    uint4 va1 = *(const uint4*)(hl + (size_t)s1 * DD);
    uint4 vb1 = *(const uint4*)(hl + (size_t)d1 * DD);

    float r0 = dot8(va0, vb0);
    float r1 = dot8(va1, vb1);
#pragma unroll
    for (int off = 8; off; off >>= 1) {
        r0 += __shfl_down(r0, off, 16);
        r1 += __shfl_down(r1, off, 16);
    }
    if (lane == 0) {
        out[e0] = r0;
        if (has1) out[e1] = r1;
    }
}

// ---------------------------------------------------------------------------

extern "C" void kernel_launch(void* const* d_in, const int* in_sizes, int n_in,
                              void* d_out, int out_size, void* d_ws, size_t ws_size,
                              hipStream_t stream)
{
    const float* feat    = (const float*)d_in[0];
    const int*   e0s     = (const int*)d_in[1];
    const int*   e0d     = (const int*)d_in[2];
    const int*   e1s     = (const int*)d_in[3];
    const int*   e1d     = (const int*)d_in[4];
    const int*   ps      = (const int*)d_in[5];
    const int*   pd      = (const int*)d_in[6];
    const int*   ns      = (const int*)d_in[7];
    const int*   nd      = (const int*)d_in[8];
    const float* w_proj  = (const float*)d_in[9];
    const float* b_proj  = (const float*)d_in[10];
    const float* w_self1 = (const float*)d_in[11];
    const float* w_neigh1= (const float*)d_in[12];
    const float* b1      = (const float*)d_in[13];
    const float* w_self2 = (const float*)d_in[14];
    const float* w_neigh2= (const float*)d_in[15];
    const float* b2      = (const float*)d_in[16];

    float* out = (float*)d_out;

    const size_t NF  = (size_t)NN * DD;
    const size_t NFP = NF + DD;          // +1 pad row (index NN, zeroed)
    char* base = (char*)d_ws;

    // bf16 buffers, NFP*2 bytes each (pad row NN for unguarded aggregate).
    ushort_t* h3   = (ushort_t*)base;
    ushort_t* h1   = h3 + NFP;
    ushort_t* mean = h1 + NFP;
    ushort_t* h2   = mean + NFP;

    uint_t* pairs  = (uint_t*)(h2 + NFP);                // 2*NB*CAPB*4 = 19.3 MB
    int*    bcnt   = (int*)(pairs + (size_t)2 * NB * CAPB);   // [2*NB]
    int*    counts = bcnt + 2 * NB;                      // [2*NN]
    int*    offs   = counts + 2 * NN;                    // [2*NN]
    ushort_t* wts  = (ushort_t*)(offs + 2 * NN);
    ushort_t* wtp = wts;                 // [128][128]
    ushort_t* wt1 = wts + 128 * 128;     // [128][256]
    ushort_t* wt2 = wt1 + 128 * 256;     // [128][256]

    const int E0 = in_sizes[1];
    const int E1 = in_sizes[3];
    const int EP = in_sizes[5];
    const int EN = in_sizes[7];

    const int GB  = (NN + 127) / 128;    // 782
    const int AGB = (NN * 16 + 255) / 256;

    // ---- Prep: weight transposes + bcnt zero + pad-row zero
    prep<<<PREP_W_BLOCKS + PREP_Z_BLOCKS, 256, 0, stream>>>(
        w_proj, w_self1, w_neigh1, w_self2, w_neigh2, wtp, wt1, wt2, bcnt,
        h1 + NF, h2 + NF);

    // ---- Build both CSRs up front
    partA2<<<2 * PA_BLOCKS, 256, 0, stream>>>(
        e0s, e0d, E0, e1s, e1d, E1, bcnt, pairs);
    partB<<<2 * NB, 256, 0, stream>>>(pairs, bcnt, counts, offs);

    // ---- Layer 0: h1 = relu(feat @ w_proj + b_proj), fp32->bf16 fused
    gemm_bf16<true, false, true><<<GB, 256, 0, stream>>>(
        feat, nullptr, wtp, b_proj, h1);

    // ---- Layer 1: mean over edge0, then dual GEMM
    aggregate_bf16<<<AGB, 256, 0, stream>>>(h1, pairs, offs, counts, mean, NN);
    gemm_bf16<true, true, false><<<GB, 256, 0, stream>>>(
        h1, mean, wt1, b1, h2);

    // ---- Layer 2: mean over edge1, then dual GEMM
    aggregate_bf16<<<AGB, 256, 0, stream>>>(
        h2, pairs, offs + NN, counts + NN, mean, NN);
    gemm_bf16<false, true, false><<<GB, 256, 0, stream>>>(
        h2, mean, wt2, b2, h3);

    // ---- Fused scoring on bf16 h3
    const int TE = EP + EN;
    const int NG = (TE + 1) / 2;
    score_both<<<(NG * 16 + 255) / 256, 256, 0, stream>>>(
        h3, ps, pd, ns, nd, out, EP, TE);
}